// Round 4
// baseline (732.392 us; speedup 1.0000x reference)
//
#include <hip/hip_runtime.h>
#include <math.h>

#define D_IN 128
typedef unsigned short ushort_t;

__device__ __forceinline__ float bf2f(ushort_t u) {
    union { unsigned i; float f; } x;
    x.i = ((unsigned)u) << 16;
    return x.f;
}
__device__ __forceinline__ ushort_t f2bf(float f) {
    unsigned i = __float_as_uint(f);
    unsigned r = (i + 0x7fffu + ((i >> 16) & 1u)) >> 16;
    return (ushort_t)r;
}

// ---------------- chunked LDS-privatized histograms ----------------
// Node range split into chunks of HCH; each block owns a private LDS histogram
// for chunk blockIdx.y over a grid-strided slice of edges, then merges with
// coalesced atomics (lines fully packed -> memory-side friendly).
#define HCH 16384

__global__ void hist_cnt_kernel(const int* __restrict__ dst, int* __restrict__ cnt,
                                int n, int E) {
    extern __shared__ int lh[];  // HCH ints
    const int base = blockIdx.y * HCH;
    const int lim = min(HCH, n - base);
    for (int i = threadIdx.x; i < HCH; i += blockDim.x) lh[i] = 0;
    __syncthreads();
    int stride = gridDim.x * blockDim.x;
    for (int e = blockIdx.x * blockDim.x + threadIdx.x; e < E; e += stride) {
        int d = dst[e] - base;
        if ((unsigned)d < (unsigned)lim) atomicAdd(&lh[d], 1);
    }
    __syncthreads();
    for (int i = threadIdx.x; i < lim; i += blockDim.x) {
        int v = lh[i];
        if (v) atomicAdd(&cnt[base + i], v);
    }
}

__global__ void hist_deg_kernel(const int* __restrict__ src, const float* __restrict__ w,
                                float* __restrict__ deg, int n, int E) {
    extern __shared__ float lhf[];  // HCH floats
    const int base = blockIdx.y * HCH;
    const int lim = min(HCH, n - base);
    for (int i = threadIdx.x; i < HCH; i += blockDim.x) lhf[i] = 0.f;
    __syncthreads();
    int stride = gridDim.x * blockDim.x;
    for (int e = blockIdx.x * blockDim.x + threadIdx.x; e < E; e += stride) {
        int s = src[e] - base;
        if ((unsigned)s < (unsigned)lim) atomicAdd(&lhf[s], w[e]);
    }
    __syncthreads();
    for (int i = threadIdx.x; i < lim; i += blockDim.x) {
        float v = lhf[i];
        if (v != 0.f) atomicAdd(&deg[base + i], v);
    }
}

__global__ void dinv_kernel(float* __restrict__ deg, int n) {
    int i = blockIdx.x * blockDim.x + threadIdx.x;
    if (i >= n) return;
    float d = deg[i];
    deg[i] = (d > 0.f) ? rsqrtf(d) : 0.f;
}

// ---------------- scan (row_ptr build) ----------------
__global__ void scan1_kernel(const int* __restrict__ cnt, int* __restrict__ incl,
                             int* __restrict__ bsum, int n) {
    __shared__ int sdata[256];
    int b = blockIdx.x, t = threadIdx.x;
    int base = b * 1024 + t * 4;
    int v[4];
    int s = 0;
#pragma unroll
    for (int k = 0; k < 4; ++k) {
        int idx = base + k;
        v[k] = (idx < n) ? cnt[idx] : 0;
        s += v[k];
    }
    sdata[t] = s;
    __syncthreads();
    for (int off = 1; off < 256; off <<= 1) {
        int y = (t >= off) ? sdata[t - off] : 0;
        __syncthreads();
        sdata[t] += y;
        __syncthreads();
    }
    int run = (t > 0) ? sdata[t - 1] : 0;
#pragma unroll
    for (int k = 0; k < 4; ++k) {
        int idx = base + k;
        run += v[k];
        if (idx < n) incl[idx] = run;
    }
    if (t == 255) bsum[b] = sdata[255];
}

__global__ void scan2_kernel(int* __restrict__ bsum, int nb) {
    __shared__ int sd[128];
    int t = threadIdx.x;
    sd[t] = (t < nb) ? bsum[t] : 0;
    __syncthreads();
    for (int off = 1; off < 128; off <<= 1) {
        int y = (t >= off) ? sd[t - off] : 0;
        __syncthreads();
        sd[t] += y;
        __syncthreads();
    }
    if (t < nb) bsum[t] = sd[t];
}

// scan3 also copies final rp into fill cursors
__global__ void scan3_kernel(int* __restrict__ incl, const int* __restrict__ bsum,
                             int n, int* __restrict__ rp, int* __restrict__ fill) {
    int b = blockIdx.x, t = threadIdx.x;
    int add = (b > 0) ? bsum[b - 1] : 0;
    int base = b * 1024 + t * 4;
#pragma unroll
    for (int k = 0; k < 4; ++k) {
        int idx = base + k;
        if (idx < n) {
            int v = incl[idx] + add;
            incl[idx] = v;          // rp[idx+1]
            if (idx + 1 < n) ;      // fill handled below with shifted index
        }
    }
    // fill[i] = rp[i] (exclusive): fill[0]=0 handled by b==0,t==0
#pragma unroll
    for (int k = 0; k < 4; ++k) {
        int idx = base + k;
        if (idx < n) {
            // rp[idx] = (idx==0) ? 0 : incl[idx-1]+add_for_that_block — incl already
            // finalized for this block's range; for idx==base (k==0,t==0) the previous
            // element belongs to another block, so recompute: safe path below.
        }
    }
    if (b == 0 && t == 0) rp[0] = 0;
}

// separate simple copy: fill[i] = rp[i]
__global__ void fill_copy_kernel(const int* __restrict__ rp, int* __restrict__ fill, int n) {
    int i = blockIdx.x * blockDim.x + threadIdx.x;
    if (i < n) fill[i] = rp[i];
}

__global__ void scatter_kernel(const int* __restrict__ src, const int* __restrict__ dst,
                               const float* __restrict__ w, const float* __restrict__ dinv,
                               int* __restrict__ fill, int2* __restrict__ cv, int E) {
    int e = blockIdx.x * blockDim.x + threadIdx.x;
    if (e >= E) return;
    int s = src[e], d = dst[e];
    float v = dinv[s] * w[e] * dinv[d];
    int o = atomicAdd(&fill[d], 1);
    int2 c;
    c.x = s;
    c.y = __float_as_int(v);
    cv[o] = c;
}

// ---------------- gemm3: m=0 -> YA=H@(W0-W2), m=1 -> YB=H@W1, m=2 -> C16=bf16(H@W2) ----------------
template <int F, int G>
__global__ __launch_bounds__(256) void gemm3(const float* __restrict__ H,
                                             const float* __restrict__ W,
                                             float* __restrict__ YA, float* __restrict__ YB,
                                             ushort_t* __restrict__ C16, int n) {
    constexpr int BK = 32;
    constexpr int CPT = G / 8;
    constexpr int KSTEPS = F / BK;
    __shared__ float Hs[BK][256];
    __shared__ float Ws[BK][G];

    const int tid = threadIdx.x;
    const int rowBase = blockIdx.x * 256;
    const int m = blockIdx.y;

    const int rg = tid & 31;
    const int cg = tid >> 5;
    const int c0 = cg * CPT;

    float acc[8][CPT];
#pragma unroll
    for (int i = 0; i < 8; ++i)
#pragma unroll
        for (int c = 0; c < CPT; ++c) acc[i][c] = 0.f;

    int gr = rowBase + tid;
    if (gr >= n) gr = n - 1;
    const float* Hrow = H + (size_t)gr * F;

    const float* W0 = W;
    const float* W2 = W + 2 * F * G;
    const float* Wm = W + (size_t)m * F * G;

    for (int ks = 0; ks < KSTEPS; ++ks) {
        const int k0 = ks * BK;
#pragma unroll
        for (int j = 0; j < BK / 4; ++j) {
            float4 hv = *(const float4*)(Hrow + k0 + j * 4);
            Hs[j * 4 + 0][tid] = hv.x;
            Hs[j * 4 + 1][tid] = hv.y;
            Hs[j * 4 + 2][tid] = hv.z;
            Hs[j * 4 + 3][tid] = hv.w;
        }
#pragma unroll
        for (int idx = 0; idx < BK * G / 256; ++idx) {
            int ii = tid + idx * 256;
            int k = ii / G, c = ii % G;
            float wv;
            if (m == 0) wv = W0[(size_t)(k0 + k) * G + c] - W2[(size_t)(k0 + k) * G + c];
            else wv = Wm[(size_t)(k0 + k) * G + c];
            Ws[k][c] = wv;
        }
        __syncthreads();
#pragma unroll
        for (int kk = 0; kk < BK; ++kk) {
            float4 ha = *(const float4*)&Hs[kk][rg * 4];
            float4 hb = *(const float4*)&Hs[kk][128 + rg * 4];
            float h[8] = {ha.x, ha.y, ha.z, ha.w, hb.x, hb.y, hb.z, hb.w};
            float w[CPT];
            if constexpr (CPT >= 4) {
#pragma unroll
                for (int c4 = 0; c4 < CPT / 4; ++c4) {
                    float4 wv = *(const float4*)&Ws[kk][c0 + c4 * 4];
                    w[c4 * 4 + 0] = wv.x;
                    w[c4 * 4 + 1] = wv.y;
                    w[c4 * 4 + 2] = wv.z;
                    w[c4 * 4 + 3] = wv.w;
                }
            } else {
                float2 wv = *(const float2*)&Ws[kk][c0];
                w[0] = wv.x;
                w[1] = wv.y;
            }
#pragma unroll
            for (int i = 0; i < 8; ++i)
#pragma unroll
                for (int c = 0; c < CPT; ++c) acc[i][c] = fmaf(h[i], w[c], acc[i][c]);
        }
        __syncthreads();
    }
#pragma unroll
    for (int half = 0; half < 2; ++half) {
#pragma unroll
        for (int i = 0; i < 4; ++i) {
            int r = rowBase + half * 128 + rg * 4 + i;
            if (r >= n) continue;
            int ai = half * 4 + i;
            if (m == 2) {
                ushort_t* dstp = C16 + (size_t)r * G + c0;
                if constexpr (CPT >= 4) {
#pragma unroll
                    for (int c4 = 0; c4 < CPT / 4; ++c4) {
                        ushort4 o;
                        o.x = f2bf(acc[ai][c4 * 4 + 0]);
                        o.y = f2bf(acc[ai][c4 * 4 + 1]);
                        o.z = f2bf(acc[ai][c4 * 4 + 2]);
                        o.w = f2bf(acc[ai][c4 * 4 + 3]);
                        *(ushort4*)(dstp + c4 * 4) = o;
                    }
                } else {
                    unsigned o = (unsigned)f2bf(acc[ai][0]) | ((unsigned)f2bf(acc[ai][1]) << 16);
                    *(unsigned*)dstp = o;
                }
            } else {
                float* dstp = (m == 0 ? YA : YB) + (size_t)r * G + c0;
                if constexpr (CPT >= 4) {
#pragma unroll
                    for (int c4 = 0; c4 < CPT / 4; ++c4) {
                        float4 o;
                        o.x = acc[ai][c4 * 4 + 0];
                        o.y = acc[ai][c4 * 4 + 1];
                        o.z = acc[ai][c4 * 4 + 2];
                        o.w = acc[ai][c4 * 4 + 3];
                        *(float4*)(dstp + c4 * 4) = o;
                    }
                } else {
                    float2 o;
                    o.x = acc[ai][0];
                    o.y = acc[ai][1];
                    *(float2*)dstp = o;
                }
            }
        }
    }
}

// ---------------- spmm with bf16 gather ----------------
template <int G, int MODE>  // MODE 1: S16 = bf16(Y - 2A@Hg); MODE 2: H = relu(Y - A@Hg + b)
__global__ __launch_bounds__(256) void spmm_bf16(const ushort_t* __restrict__ Hg,
                                                 const float* __restrict__ Yres,
                                                 const float* __restrict__ bias,
                                                 ushort_t* __restrict__ outS,
                                                 float* __restrict__ outH,
                                                 const int2* __restrict__ cv,
                                                 const int* __restrict__ rp, int n) {
    constexpr int TPR = G / 4;
    constexpr int RPB = 256 / TPR;
    int row = blockIdx.x * RPB + threadIdx.x / TPR;
    if (row >= n) return;
    int g = (threadIdx.x % TPR) * 4;
    float a0 = 0.f, a1 = 0.f, a2 = 0.f, a3 = 0.f;
    int e1 = rp[row + 1];
    for (int e = rp[row]; e < e1; ++e) {
        int2 c = cv[e];
        float v = __int_as_float(c.y);
        ushort4 hv = *(const ushort4*)(Hg + (size_t)c.x * G + g);
        a0 = fmaf(v, bf2f(hv.x), a0);
        a1 = fmaf(v, bf2f(hv.y), a1);
        a2 = fmaf(v, bf2f(hv.z), a2);
        a3 = fmaf(v, bf2f(hv.w), a3);
    }
    float4 yv = *(const float4*)(Yres + (size_t)row * G + g);
    if (MODE == 1) {
        ushort4 o;
        o.x = f2bf(yv.x - 2.f * a0);
        o.y = f2bf(yv.y - 2.f * a1);
        o.z = f2bf(yv.z - 2.f * a2);
        o.w = f2bf(yv.w - 2.f * a3);
        *(ushort4*)(outS + (size_t)row * G + g) = o;
    } else {
        float4 o;
        o.x = fmaxf(yv.x - a0 + bias[g + 0], 0.f);
        o.y = fmaxf(yv.y - a1 + bias[g + 1], 0.f);
        o.z = fmaxf(yv.z - a2 + bias[g + 2], 0.f);
        o.w = fmaxf(yv.w - a3 + bias[g + 3], 0.f);
        *(float4*)(outH + (size_t)row * G + g) = o;
    }
}

// ---------------- layer 4 (fp32; gather targets L2-resident) ----------------

__global__ void gemm4(const float* __restrict__ H, const float* __restrict__ W,
                      float* __restrict__ YA, float* __restrict__ YB, float* __restrict__ C,
                      int n) {
    __shared__ float Ws[3 * 16 * 4];
    if (threadIdx.x < 192) Ws[threadIdx.x] = W[threadIdx.x];
    __syncthreads();
    int i = blockIdx.x * blockDim.x + threadIdx.x;
    if (i >= n) return;
    const float* h = H + (size_t)i * 16;
    float a[4], b[4], c[4];
#pragma unroll
    for (int g = 0; g < 4; ++g) a[g] = b[g] = c[g] = 0.f;
#pragma unroll
    for (int j = 0; j < 4; ++j) {
        float4 hv = *(const float4*)(h + j * 4);
        float hf[4] = {hv.x, hv.y, hv.z, hv.w};
#pragma unroll
        for (int k = 0; k < 4; ++k) {
            int f = j * 4 + k;
#pragma unroll
            for (int g = 0; g < 4; ++g) {
                a[g] = fmaf(hf[k], Ws[f * 4 + g], a[g]);
                b[g] = fmaf(hf[k], Ws[64 + f * 4 + g], b[g]);
                c[g] = fmaf(hf[k], Ws[128 + f * 4 + g], c[g]);
            }
        }
    }
    float4 oa, ob, oc;
    oa.x = a[0] - c[0]; oa.y = a[1] - c[1]; oa.z = a[2] - c[2]; oa.w = a[3] - c[3];
    ob.x = b[0]; ob.y = b[1]; ob.z = b[2]; ob.w = b[3];
    oc.x = c[0]; oc.y = c[1]; oc.z = c[2]; oc.w = c[3];
    *(float4*)(YA + (size_t)i * 4) = oa;
    *(float4*)(YB + (size_t)i * 4) = ob;
    *(float4*)(C + (size_t)i * 4) = oc;
}

__global__ void spmm4(const float* __restrict__ C, const float* __restrict__ YB,
                      float* __restrict__ S, const int2* __restrict__ cv,
                      const int* __restrict__ rp, int n) {
    int row = blockIdx.x * blockDim.x + threadIdx.x;
    if (row >= n) return;
    float a0 = 0.f, a1 = 0.f, a2 = 0.f, a3 = 0.f;
    int e1 = rp[row + 1];
    for (int e = rp[row]; e < e1; ++e) {
        int2 c = cv[e];
        float v = __int_as_float(c.y);
        float4 cvv = *(const float4*)(C + (size_t)c.x * 4);
        a0 = fmaf(v, cvv.x, a0);
        a1 = fmaf(v, cvv.y, a1);
        a2 = fmaf(v, cvv.z, a2);
        a3 = fmaf(v, cvv.w, a3);
    }
    float4 yb = *(const float4*)(YB + (size_t)row * 4);
    float4 o;
    o.x = yb.x - 2.f * a0;
    o.y = yb.y - 2.f * a1;
    o.z = yb.z - 2.f * a2;
    o.w = yb.w - 2.f * a3;
    *(float4*)(S + (size_t)row * 4) = o;
}

__global__ void layer4_final(const float* __restrict__ S, const float* __restrict__ YA,
                             const float* __restrict__ b, float* __restrict__ out,
                             const int2* __restrict__ cv, const int* __restrict__ rp, int n) {
    int row = blockIdx.x * blockDim.x + threadIdx.x;
    if (row >= n) return;
    float a0 = 0.f, a1 = 0.f, a2 = 0.f, a3 = 0.f;
    int e1 = rp[row + 1];
    for (int e = rp[row]; e < e1; ++e) {
        int2 c = cv[e];
        float v = __int_as_float(c.y);
        float4 sv = *(const float4*)(S + (size_t)c.x * 4);
        a0 = fmaf(v, sv.x, a0);
        a1 = fmaf(v, sv.y, a1);
        a2 = fmaf(v, sv.z, a2);
        a3 = fmaf(v, sv.w, a3);
    }
    float4 ya = *(const float4*)(YA + (size_t)row * 4);
    float o0 = ya.x - a0 + b[0];
    float o1 = ya.y - a1 + b[1];
    float o2 = ya.z - a2 + b[2];
    float o3 = ya.w - a3 + b[3];
    float m = fmaxf(fmaxf(o0, o1), fmaxf(o2, o3));
    float s = expf(o0 - m) + expf(o1 - m) + expf(o2 - m) + expf(o3 - m);
    float ls = m + logf(s);
    float4 r;
    r.x = o0 - ls;
    r.y = o1 - ls;
    r.z = o2 - ls;
    r.w = o3 - ls;
    *(float4*)(out + (size_t)row * 4) = r;
}

// ---------------- launch ----------------

static inline char* align_up(char* p, size_t a) {
    return (char*)(((uintptr_t)p + a - 1) & ~(uintptr_t)(a - 1));
}

extern "C" void kernel_launch(void* const* d_in, const int* in_sizes, int n_in,
                              void* d_out, int out_size, void* d_ws, size_t ws_size,
                              hipStream_t stream) {
    const float* x = (const float*)d_in[0];
    const int* ei = (const int*)d_in[1];
    const float* ew = (const float*)d_in[2];
    const float* W1 = (const float*)d_in[3];
    const float* b1 = (const float*)d_in[4];
    const float* W2 = (const float*)d_in[5];
    const float* b2 = (const float*)d_in[6];
    const float* W3 = (const float*)d_in[7];
    const float* b3 = (const float*)d_in[8];
    const float* W4 = (const float*)d_in[9];
    const float* b4 = (const float*)d_in[10];
    float* out = (float*)d_out;

    const int n = in_sizes[0] / D_IN;  // 100000
    const int E = in_sizes[2];         // 1600000
    const int* src = ei;
    const int* dst = ei + E;

    char* p = (char*)d_ws;
    int2* cv = (int2*)p;       p += (size_t)E * 8;
    float* deg = (float*)p;    p += (size_t)n * 4;
    int* cnt = (int*)p;        p += (size_t)n * 4;
    int* fill = (int*)p;       p += (size_t)n * 4;
    int* rp = (int*)p;         p = align_up(p + (size_t)(n + 1) * 4, 64);
    int* bsum = (int*)p;       p = align_up(p + 512, 64);
    float* YA = (float*)p;     p = align_up(p + (size_t)n * 64 * 4, 64);
    float* YB = (float*)p;     p = align_up(p + (size_t)n * 64 * 4, 64);
    ushort_t* C16 = (ushort_t*)p; p = align_up(p + (size_t)n * 64 * 2, 64);
    ushort_t* S16 = (ushort_t*)p; p = align_up(p + (size_t)n * 64 * 2, 64);
    float* H1 = (float*)p;     p = align_up(p + (size_t)n * 64 * 4, 64);
    float* H2 = (float*)p;     p = align_up(p + (size_t)n * 32 * 4, 64);
    float* H3 = (float*)p;     p = align_up(p + (size_t)n * 16 * 4, 64);
    float* YA4 = (float*)p;    p = align_up(p + (size_t)n * 4 * 4, 64);
    float* YB4 = (float*)p;    p = align_up(p + (size_t)n * 4 * 4, 64);
    float* C4 = (float*)p;     p = align_up(p + (size_t)n * 4 * 4, 64);
    float* S4 = (float*)p;     p = align_up(p + (size_t)n * 4 * 4, 64);

    const int TB = 256;
    int eb = (E + TB - 1) / TB;
    int nb256 = (n + TB - 1) / TB;
    int nscan = (n + 1023) / 1024;
    int nch = (n + HCH - 1) / HCH;

    hipMemsetAsync(deg, 0, (size_t)n * 4, stream);
    hipMemsetAsync(cnt, 0, (size_t)n * 4, stream);
    {
        dim3 hg(32, nch);
        hist_cnt_kernel<<<hg, 256, HCH * 4, stream>>>(dst, cnt, n, E);
        hist_deg_kernel<<<hg, 256, HCH * 4, stream>>>(src, ew, deg, n, E);
    }
    dinv_kernel<<<nb256, TB, 0, stream>>>(deg, n);
    scan1_kernel<<<nscan, 256, 0, stream>>>(cnt, rp + 1, bsum, n);
    scan2_kernel<<<1, 128, 0, stream>>>(bsum, nscan);
    scan3_kernel<<<nscan, 256, 0, stream>>>(rp + 1, bsum, n, rp, nullptr);
    fill_copy_kernel<<<nb256, TB, 0, stream>>>(rp, fill, n);
    scatter_kernel<<<eb, TB, 0, stream>>>(src, dst, ew, deg, fill, cv, E);

    // ---- layer 1: F=128, G=64 ----
    {
        constexpr int F = 128, G = 64;
        dim3 gg((n + 255) / 256, 3);
        gemm3<F, G><<<gg, 256, 0, stream>>>(x, W1, YA, YB, C16, n);
        int sb = (n + (1024 / G) - 1) / (1024 / G);
        spmm_bf16<G, 1><<<sb, 256, 0, stream>>>(C16, YB, nullptr, S16, nullptr, cv, rp, n);
        spmm_bf16<G, 2><<<sb, 256, 0, stream>>>(S16, YA, b1, nullptr, H1, cv, rp, n);
    }
    // ---- layer 2: F=64, G=32 ----
    {
        constexpr int F = 64, G = 32;
        dim3 gg((n + 255) / 256, 3);
        gemm3<F, G><<<gg, 256, 0, stream>>>(H1, W2, YA, YB, C16, n);
        int sb = (n + (1024 / G) - 1) / (1024 / G);
        spmm_bf16<G, 1><<<sb, 256, 0, stream>>>(C16, YB, nullptr, S16, nullptr, cv, rp, n);
        spmm_bf16<G, 2><<<sb, 256, 0, stream>>>(S16, YA, b2, nullptr, H2, cv, rp, n);
    }
    // ---- layer 3: F=32, G=16 ----
    {
        constexpr int F = 32, G = 16;
        dim3 gg((n + 255) / 256, 3);
        gemm3<F, G><<<gg, 256, 0, stream>>>(H2, W3, YA, YB, C16, n);
        int sb = (n + (1024 / G) - 1) / (1024 / G);
        spmm_bf16<G, 1><<<sb, 256, 0, stream>>>(C16, YB, nullptr, S16, nullptr, cv, rp, n);
        spmm_bf16<G, 2><<<sb, 256, 0, stream>>>(S16, YA, b3, nullptr, H3, cv, rp, n);
    }
    // ---- layer 4: F=16, G=4 (fp32) ----
    {
        gemm4<<<nb256, 256, 0, stream>>>(H3, W4, YA4, YB4, C4, n);
        spmm4<<<nb256, 256, 0, stream>>>(C4, YB4, S4, cv, rp, n);
        layer4_final<<<nb256, 256, 0, stream>>>(S4, YA4, b4, out, cv, rp, n);
    }
}

// Round 5
// 697.329 us; speedup vs baseline: 1.0503x; 1.0503x over previous
//
#include <hip/hip_runtime.h>
#include <math.h>

#define D_IN 128
typedef unsigned short ushort_t;

__device__ __forceinline__ float bf2f(ushort_t u) {
    union { unsigned i; float f; } x;
    x.i = ((unsigned)u) << 16;
    return x.f;
}
__device__ __forceinline__ ushort_t f2bf(float f) {
    unsigned i = __float_as_uint(f);
    unsigned r = (i + 0x7fffu + ((i >> 16) & 1u)) >> 16;
    return (ushort_t)r;
}

// ---------------- chunked LDS-privatized histograms ----------------
// HCH=8192 (32KB LDS) -> ~5 resident blocks/CU; gridDim.x=128 spreads each
// chunk's edge scan across 32K threads (latency-bound fix, round 4).
#define HCH 8192

__global__ void hist_cnt_kernel(const int* __restrict__ dst, int* __restrict__ cnt,
                                int n, int E) {
    __shared__ int lh[HCH];
    const int base = blockIdx.y * HCH;
    const int lim = min(HCH, n - base);
    for (int i = threadIdx.x; i < HCH; i += blockDim.x) lh[i] = 0;
    __syncthreads();
    int stride = gridDim.x * blockDim.x;
    for (int e = blockIdx.x * blockDim.x + threadIdx.x; e < E; e += stride) {
        int d = dst[e] - base;
        if ((unsigned)d < (unsigned)lim) atomicAdd(&lh[d], 1);
    }
    __syncthreads();
    for (int i = threadIdx.x; i < lim; i += blockDim.x) {
        int v = lh[i];
        if (v) atomicAdd(&cnt[base + i], v);
    }
}

__global__ void hist_deg_kernel(const int* __restrict__ src, const float* __restrict__ w,
                                float* __restrict__ deg, int n, int E) {
    __shared__ float lhf[HCH];
    const int base = blockIdx.y * HCH;
    const int lim = min(HCH, n - base);
    for (int i = threadIdx.x; i < HCH; i += blockDim.x) lhf[i] = 0.f;
    __syncthreads();
    int stride = gridDim.x * blockDim.x;
    for (int e = blockIdx.x * blockDim.x + threadIdx.x; e < E; e += stride) {
        int s = src[e] - base;
        if ((unsigned)s < (unsigned)lim) atomicAdd(&lhf[s], w[e]);
    }
    __syncthreads();
    for (int i = threadIdx.x; i < lim; i += blockDim.x) {
        float v = lhf[i];
        if (v != 0.f) atomicAdd(&deg[base + i], v);
    }
}

__global__ void dinv_kernel(float* __restrict__ deg, int n) {
    int i = blockIdx.x * blockDim.x + threadIdx.x;
    if (i >= n) return;
    float d = deg[i];
    deg[i] = (d > 0.f) ? rsqrtf(d) : 0.f;
}

// ---------------- scan (row_ptr build) ----------------
__global__ void scan1_kernel(const int* __restrict__ cnt, int* __restrict__ incl,
                             int* __restrict__ bsum, int n) {
    __shared__ int sdata[256];
    int b = blockIdx.x, t = threadIdx.x;
    int base = b * 1024 + t * 4;
    int v[4];
    int s = 0;
#pragma unroll
    for (int k = 0; k < 4; ++k) {
        int idx = base + k;
        v[k] = (idx < n) ? cnt[idx] : 0;
        s += v[k];
    }
    sdata[t] = s;
    __syncthreads();
    for (int off = 1; off < 256; off <<= 1) {
        int y = (t >= off) ? sdata[t - off] : 0;
        __syncthreads();
        sdata[t] += y;
        __syncthreads();
    }
    int run = (t > 0) ? sdata[t - 1] : 0;
#pragma unroll
    for (int k = 0; k < 4; ++k) {
        int idx = base + k;
        run += v[k];
        if (idx < n) incl[idx] = run;
    }
    if (t == 255) bsum[b] = sdata[255];
}

__global__ void scan2_kernel(int* __restrict__ bsum, int nb) {
    __shared__ int sd[128];
    int t = threadIdx.x;
    sd[t] = (t < nb) ? bsum[t] : 0;
    __syncthreads();
    for (int off = 1; off < 128; off <<= 1) {
        int y = (t >= off) ? sd[t - off] : 0;
        __syncthreads();
        sd[t] += y;
        __syncthreads();
    }
    if (t < nb) bsum[t] = sd[t];
}

__global__ void scan3_kernel(int* __restrict__ incl, const int* __restrict__ bsum,
                             int n, int* __restrict__ rp) {
    int b = blockIdx.x, t = threadIdx.x;
    int add = (b > 0) ? bsum[b - 1] : 0;
    int base = b * 1024 + t * 4;
#pragma unroll
    for (int k = 0; k < 4; ++k) {
        int idx = base + k;
        if (idx < n) incl[idx] += add;
    }
    if (b == 0 && t == 0) rp[0] = 0;
}

__global__ void fill_copy_kernel(const int* __restrict__ rp, int* __restrict__ fill, int n) {
    int i = blockIdx.x * blockDim.x + threadIdx.x;
    if (i < n) fill[i] = rp[i];
}

__global__ void scatter_kernel(const int* __restrict__ src, const int* __restrict__ dst,
                               const float* __restrict__ w, const float* __restrict__ dinv,
                               int* __restrict__ fill, int2* __restrict__ cv, int E) {
    int e = blockIdx.x * blockDim.x + threadIdx.x;
    if (e >= E) return;
    int s = src[e], d = dst[e];
    float v = dinv[s] * w[e] * dinv[d];
    int o = atomicAdd(&fill[d], 1);
    int2 c;
    c.x = s;
    c.y = __float_as_int(v);
    cv[o] = c;
}

// ---------------- gemm3: m=0 -> YA=H@(W0-W2), m=1 -> YB=H@W1, m=2 -> C16=bf16(H@W2) ----------------
template <int F, int G>
__global__ __launch_bounds__(256) void gemm3(const float* __restrict__ H,
                                             const float* __restrict__ W,
                                             float* __restrict__ YA, float* __restrict__ YB,
                                             ushort_t* __restrict__ C16, int n) {
    constexpr int BK = 32;
    constexpr int CPT = G / 8;
    constexpr int KSTEPS = F / BK;
    __shared__ float Hs[BK][256];
    __shared__ float Ws[BK][G];

    const int tid = threadIdx.x;
    const int rowBase = blockIdx.x * 256;
    const int m = blockIdx.y;

    const int rg = tid & 31;
    const int cg = tid >> 5;
    const int c0 = cg * CPT;

    float acc[8][CPT];
#pragma unroll
    for (int i = 0; i < 8; ++i)
#pragma unroll
        for (int c = 0; c < CPT; ++c) acc[i][c] = 0.f;

    int gr = rowBase + tid;
    if (gr >= n) gr = n - 1;
    const float* Hrow = H + (size_t)gr * F;

    const float* W0 = W;
    const float* W2 = W + 2 * F * G;
    const float* Wm = W + (size_t)m * F * G;

    for (int ks = 0; ks < KSTEPS; ++ks) {
        const int k0 = ks * BK;
#pragma unroll
        for (int j = 0; j < BK / 4; ++j) {
            float4 hv = *(const float4*)(Hrow + k0 + j * 4);
            Hs[j * 4 + 0][tid] = hv.x;
            Hs[j * 4 + 1][tid] = hv.y;
            Hs[j * 4 + 2][tid] = hv.z;
            Hs[j * 4 + 3][tid] = hv.w;
        }
#pragma unroll
        for (int idx = 0; idx < BK * G / 256; ++idx) {
            int ii = tid + idx * 256;
            int k = ii / G, c = ii % G;
            float wv;
            if (m == 0) wv = W0[(size_t)(k0 + k) * G + c] - W2[(size_t)(k0 + k) * G + c];
            else wv = Wm[(size_t)(k0 + k) * G + c];
            Ws[k][c] = wv;
        }
        __syncthreads();
#pragma unroll
        for (int kk = 0; kk < BK; ++kk) {
            float4 ha = *(const float4*)&Hs[kk][rg * 4];
            float4 hb = *(const float4*)&Hs[kk][128 + rg * 4];
            float h[8] = {ha.x, ha.y, ha.z, ha.w, hb.x, hb.y, hb.z, hb.w};
            float w[CPT];
            if constexpr (CPT >= 4) {
#pragma unroll
                for (int c4 = 0; c4 < CPT / 4; ++c4) {
                    float4 wv = *(const float4*)&Ws[kk][c0 + c4 * 4];
                    w[c4 * 4 + 0] = wv.x;
                    w[c4 * 4 + 1] = wv.y;
                    w[c4 * 4 + 2] = wv.z;
                    w[c4 * 4 + 3] = wv.w;
                }
            } else {
                float2 wv = *(const float2*)&Ws[kk][c0];
                w[0] = wv.x;
                w[1] = wv.y;
            }
#pragma unroll
            for (int i = 0; i < 8; ++i)
#pragma unroll
                for (int c = 0; c < CPT; ++c) acc[i][c] = fmaf(h[i], w[c], acc[i][c]);
        }
        __syncthreads();
    }
#pragma unroll
    for (int half = 0; half < 2; ++half) {
#pragma unroll
        for (int i = 0; i < 4; ++i) {
            int r = rowBase + half * 128 + rg * 4 + i;
            if (r >= n) continue;
            int ai = half * 4 + i;
            if (m == 2) {
                ushort_t* dstp = C16 + (size_t)r * G + c0;
                if constexpr (CPT >= 4) {
#pragma unroll
                    for (int c4 = 0; c4 < CPT / 4; ++c4) {
                        ushort4 o;
                        o.x = f2bf(acc[ai][c4 * 4 + 0]);
                        o.y = f2bf(acc[ai][c4 * 4 + 1]);
                        o.z = f2bf(acc[ai][c4 * 4 + 2]);
                        o.w = f2bf(acc[ai][c4 * 4 + 3]);
                        *(ushort4*)(dstp + c4 * 4) = o;
                    }
                } else {
                    unsigned o = (unsigned)f2bf(acc[ai][0]) | ((unsigned)f2bf(acc[ai][1]) << 16);
                    *(unsigned*)dstp = o;
                }
            } else {
                float* dstp = (m == 0 ? YA : YB) + (size_t)r * G + c0;
                if constexpr (CPT >= 4) {
#pragma unroll
                    for (int c4 = 0; c4 < CPT / 4; ++c4) {
                        float4 o;
                        o.x = acc[ai][c4 * 4 + 0];
                        o.y = acc[ai][c4 * 4 + 1];
                        o.z = acc[ai][c4 * 4 + 2];
                        o.w = acc[ai][c4 * 4 + 3];
                        *(float4*)(dstp + c4 * 4) = o;
                    }
                } else {
                    float2 o;
                    o.x = acc[ai][0];
                    o.y = acc[ai][1];
                    *(float2*)dstp = o;
                }
            }
        }
    }
}

// ---------------- spmm with bf16 gather ----------------
template <int G, int MODE>  // MODE 1: S16 = bf16(Y - 2A@Hg); MODE 2: H = relu(Y - A@Hg + b)
__global__ __launch_bounds__(256) void spmm_bf16(const ushort_t* __restrict__ Hg,
                                                 const float* __restrict__ Yres,
                                                 const float* __restrict__ bias,
                                                 ushort_t* __restrict__ outS,
                                                 float* __restrict__ outH,
                                                 const int2* __restrict__ cv,
                                                 const int* __restrict__ rp, int n) {
    constexpr int TPR = G / 4;
    constexpr int RPB = 256 / TPR;
    int row = blockIdx.x * RPB + threadIdx.x / TPR;
    if (row >= n) return;
    int g = (threadIdx.x % TPR) * 4;
    float a0 = 0.f, a1 = 0.f, a2 = 0.f, a3 = 0.f;
    int e1 = rp[row + 1];
    for (int e = rp[row]; e < e1; ++e) {
        int2 c = cv[e];
        float v = __int_as_float(c.y);
        ushort4 hv = *(const ushort4*)(Hg + (size_t)c.x * G + g);
        a0 = fmaf(v, bf2f(hv.x), a0);
        a1 = fmaf(v, bf2f(hv.y), a1);
        a2 = fmaf(v, bf2f(hv.z), a2);
        a3 = fmaf(v, bf2f(hv.w), a3);
    }
    float4 yv = *(const float4*)(Yres + (size_t)row * G + g);
    if (MODE == 1) {
        ushort4 o;
        o.x = f2bf(yv.x - 2.f * a0);
        o.y = f2bf(yv.y - 2.f * a1);
        o.z = f2bf(yv.z - 2.f * a2);
        o.w = f2bf(yv.w - 2.f * a3);
        *(ushort4*)(outS + (size_t)row * G + g) = o;
    } else {
        float4 o;
        o.x = fmaxf(yv.x - a0 + bias[g + 0], 0.f);
        o.y = fmaxf(yv.y - a1 + bias[g + 1], 0.f);
        o.z = fmaxf(yv.z - a2 + bias[g + 2], 0.f);
        o.w = fmaxf(yv.w - a3 + bias[g + 3], 0.f);
        *(float4*)(outH + (size_t)row * G + g) = o;
    }
}

// ---------------- layer 4 (fp32; gather targets L2-resident) ----------------

__global__ void gemm4(const float* __restrict__ H, const float* __restrict__ W,
                      float* __restrict__ YA, float* __restrict__ YB, float* __restrict__ C,
                      int n) {
    __shared__ float Ws[3 * 16 * 4];
    if (threadIdx.x < 192) Ws[threadIdx.x] = W[threadIdx.x];
    __syncthreads();
    int i = blockIdx.x * blockDim.x + threadIdx.x;
    if (i >= n) return;
    const float* h = H + (size_t)i * 16;
    float a[4], b[4], c[4];
#pragma unroll
    for (int g = 0; g < 4; ++g) a[g] = b[g] = c[g] = 0.f;
#pragma unroll
    for (int j = 0; j < 4; ++j) {
        float4 hv = *(const float4*)(h + j * 4);
        float hf[4] = {hv.x, hv.y, hv.z, hv.w};
#pragma unroll
        for (int k = 0; k < 4; ++k) {
            int f = j * 4 + k;
#pragma unroll
            for (int g = 0; g < 4; ++g) {
                a[g] = fmaf(hf[k], Ws[f * 4 + g], a[g]);
                b[g] = fmaf(hf[k], Ws[64 + f * 4 + g], b[g]);
                c[g] = fmaf(hf[k], Ws[128 + f * 4 + g], c[g]);
            }
        }
    }
    float4 oa, ob, oc;
    oa.x = a[0] - c[0]; oa.y = a[1] - c[1]; oa.z = a[2] - c[2]; oa.w = a[3] - c[3];
    ob.x = b[0]; ob.y = b[1]; ob.z = b[2]; ob.w = b[3];
    oc.x = c[0]; oc.y = c[1]; oc.z = c[2]; oc.w = c[3];
    *(float4*)(YA + (size_t)i * 4) = oa;
    *(float4*)(YB + (size_t)i * 4) = ob;
    *(float4*)(C + (size_t)i * 4) = oc;
}

__global__ void spmm4(const float* __restrict__ C, const float* __restrict__ YB,
                      float* __restrict__ S, const int2* __restrict__ cv,
                      const int* __restrict__ rp, int n) {
    int row = blockIdx.x * blockDim.x + threadIdx.x;
    if (row >= n) return;
    float a0 = 0.f, a1 = 0.f, a2 = 0.f, a3 = 0.f;
    int e1 = rp[row + 1];
    for (int e = rp[row]; e < e1; ++e) {
        int2 c = cv[e];
        float v = __int_as_float(c.y);
        float4 cvv = *(const float4*)(C + (size_t)c.x * 4);
        a0 = fmaf(v, cvv.x, a0);
        a1 = fmaf(v, cvv.y, a1);
        a2 = fmaf(v, cvv.z, a2);
        a3 = fmaf(v, cvv.w, a3);
    }
    float4 yb = *(const float4*)(YB + (size_t)row * 4);
    float4 o;
    o.x = yb.x - 2.f * a0;
    o.y = yb.y - 2.f * a1;
    o.z = yb.z - 2.f * a2;
    o.w = yb.w - 2.f * a3;
    *(float4*)(S + (size_t)row * 4) = o;
}

__global__ void layer4_final(const float* __restrict__ S, const float* __restrict__ YA,
                             const float* __restrict__ b, float* __restrict__ out,
                             const int2* __restrict__ cv, const int* __restrict__ rp, int n) {
    int row = blockIdx.x * blockDim.x + threadIdx.x;
    if (row >= n) return;
    float a0 = 0.f, a1 = 0.f, a2 = 0.f, a3 = 0.f;
    int e1 = rp[row + 1];
    for (int e = rp[row]; e < e1; ++e) {
        int2 c = cv[e];
        float v = __int_as_float(c.y);
        float4 sv = *(const float4*)(S + (size_t)c.x * 4);
        a0 = fmaf(v, sv.x, a0);
        a1 = fmaf(v, sv.y, a1);
        a2 = fmaf(v, sv.z, a2);
        a3 = fmaf(v, sv.w, a3);
    }
    float4 ya = *(const float4*)(YA + (size_t)row * 4);
    float o0 = ya.x - a0 + b[0];
    float o1 = ya.y - a1 + b[1];
    float o2 = ya.z - a2 + b[2];
    float o3 = ya.w - a3 + b[3];
    float m = fmaxf(fmaxf(o0, o1), fmaxf(o2, o3));
    float s = expf(o0 - m) + expf(o1 - m) + expf(o2 - m) + expf(o3 - m);
    float ls = m + logf(s);
    float4 r;
    r.x = o0 - ls;
    r.y = o1 - ls;
    r.z = o2 - ls;
    r.w = o3 - ls;
    *(float4*)(out + (size_t)row * 4) = r;
}

// ---------------- launch ----------------

static inline char* align_up(char* p, size_t a) {
    return (char*)(((uintptr_t)p + a - 1) & ~(uintptr_t)(a - 1));
}

extern "C" void kernel_launch(void* const* d_in, const int* in_sizes, int n_in,
                              void* d_out, int out_size, void* d_ws, size_t ws_size,
                              hipStream_t stream) {
    const float* x = (const float*)d_in[0];
    const int* ei = (const int*)d_in[1];
    const float* ew = (const float*)d_in[2];
    const float* W1 = (const float*)d_in[3];
    const float* b1 = (const float*)d_in[4];
    const float* W2 = (const float*)d_in[5];
    const float* b2 = (const float*)d_in[6];
    const float* W3 = (const float*)d_in[7];
    const float* b3 = (const float*)d_in[8];
    const float* W4 = (const float*)d_in[9];
    const float* b4 = (const float*)d_in[10];
    float* out = (float*)d_out;

    const int n = in_sizes[0] / D_IN;  // 100000
    const int E = in_sizes[2];         // 1600000
    const int* src = ei;
    const int* dst = ei + E;

    char* p = (char*)d_ws;
    int2* cv = (int2*)p;       p += (size_t)E * 8;
    float* deg = (float*)p;    p += (size_t)n * 4;
    int* cnt = (int*)p;        p += (size_t)n * 4;
    int* fill = (int*)p;       p += (size_t)n * 4;
    int* rp = (int*)p;         p = align_up(p + (size_t)(n + 1) * 4, 64);
    int* bsum = (int*)p;       p = align_up(p + 512, 64);
    float* YA = (float*)p;     p = align_up(p + (size_t)n * 64 * 4, 64);
    float* YB = (float*)p;     p = align_up(p + (size_t)n * 64 * 4, 64);
    ushort_t* C16 = (ushort_t*)p; p = align_up(p + (size_t)n * 64 * 2, 64);
    ushort_t* S16 = (ushort_t*)p; p = align_up(p + (size_t)n * 64 * 2, 64);
    float* H1 = (float*)p;     p = align_up(p + (size_t)n * 64 * 4, 64);
    float* H2 = (float*)p;     p = align_up(p + (size_t)n * 32 * 4, 64);
    float* H3 = (float*)p;     p = align_up(p + (size_t)n * 16 * 4, 64);
    float* YA4 = (float*)p;    p = align_up(p + (size_t)n * 4 * 4, 64);
    float* YB4 = (float*)p;    p = align_up(p + (size_t)n * 4 * 4, 64);
    float* C4 = (float*)p;     p = align_up(p + (size_t)n * 4 * 4, 64);
    float* S4 = (float*)p;     p = align_up(p + (size_t)n * 4 * 4, 64);

    const int TB = 256;
    int eb = (E + TB - 1) / TB;
    int nb256 = (n + TB - 1) / TB;
    int nscan = (n + 1023) / 1024;
    int nch = (n + HCH - 1) / HCH;

    hipMemsetAsync(deg, 0, (size_t)n * 4, stream);
    hipMemsetAsync(cnt, 0, (size_t)n * 4, stream);
    {
        dim3 hg(128, nch);
        hist_cnt_kernel<<<hg, 256, 0, stream>>>(dst, cnt, n, E);
        hist_deg_kernel<<<hg, 256, 0, stream>>>(src, ew, deg, n, E);
    }
    dinv_kernel<<<nb256, TB, 0, stream>>>(deg, n);
    scan1_kernel<<<nscan, 256, 0, stream>>>(cnt, rp + 1, bsum, n);
    scan2_kernel<<<1, 128, 0, stream>>>(bsum, nscan);
    scan3_kernel<<<nscan, 256, 0, stream>>>(rp + 1, bsum, n, rp);
    fill_copy_kernel<<<nb256, TB, 0, stream>>>(rp, fill, n);
    scatter_kernel<<<eb, TB, 0, stream>>>(src, dst, ew, deg, fill, cv, E);

    // ---- layer 1: F=128, G=64 ----
    {
        constexpr int F = 128, G = 64;
        dim3 gg((n + 255) / 256, 3);
        gemm3<F, G><<<gg, 256, 0, stream>>>(x, W1, YA, YB, C16, n);
        int sb = (n + (1024 / G) - 1) / (1024 / G);
        spmm_bf16<G, 1><<<sb, 256, 0, stream>>>(C16, YB, nullptr, S16, nullptr, cv, rp, n);
        spmm_bf16<G, 2><<<sb, 256, 0, stream>>>(S16, YA, b1, nullptr, H1, cv, rp, n);
    }
    // ---- layer 2: F=64, G=32 ----
    {
        constexpr int F = 64, G = 32;
        dim3 gg((n + 255) / 256, 3);
        gemm3<F, G><<<gg, 256, 0, stream>>>(H1, W2, YA, YB, C16, n);
        int sb = (n + (1024 / G) - 1) / (1024 / G);
        spmm_bf16<G, 1><<<sb, 256, 0, stream>>>(C16, YB, nullptr, S16, nullptr, cv, rp, n);
        spmm_bf16<G, 2><<<sb, 256, 0, stream>>>(S16, YA, b2, nullptr, H2, cv, rp, n);
    }
    // ---- layer 3: F=32, G=16 ----
    {
        constexpr int F = 32, G = 16;
        dim3 gg((n + 255) / 256, 3);
        gemm3<F, G><<<gg, 256, 0, stream>>>(H2, W3, YA, YB, C16, n);
        int sb = (n + (1024 / G) - 1) / (1024 / G);
        spmm_bf16<G, 1><<<sb, 256, 0, stream>>>(C16, YB, nullptr, S16, nullptr, cv, rp, n);
        spmm_bf16<G, 2><<<sb, 256, 0, stream>>>(S16, YA, b3, nullptr, H3, cv, rp, n);
    }
    // ---- layer 4: F=16, G=4 (fp32) ----
    {
        gemm4<<<nb256, 256, 0, stream>>>(H3, W4, YA4, YB4, C4, n);
        spmm4<<<nb256, 256, 0, stream>>>(C4, YB4, S4, cv, rp, n);
        layer4_final<<<nb256, 256, 0, stream>>>(S4, YA4, b4, out, cv, rp, n);
    }
}

// Round 6
// 611.225 us; speedup vs baseline: 1.1982x; 1.1409x over previous
//
#include <hip/hip_runtime.h>
#include <math.h>

#define D_IN 128
typedef unsigned short ushort_t;
typedef __attribute__((ext_vector_type(8))) short short8;
typedef __attribute__((ext_vector_type(4))) float f32x4;

__device__ __forceinline__ float bf2f(ushort_t u) {
    union { unsigned i; float f; } x;
    x.i = ((unsigned)u) << 16;
    return x.f;
}
__device__ __forceinline__ ushort_t f2bf(float f) {
    unsigned i = __float_as_uint(f);
    unsigned r = (i + 0x7fffu + ((i >> 16) & 1u)) >> 16;
    return (ushort_t)r;
}

// ---------------- chunked LDS-privatized histograms ----------------
#define HCH 8192

__global__ void hist_cnt_kernel(const int* __restrict__ dst, int* __restrict__ cnt,
                                int n, int E) {
    __shared__ int lh[HCH];
    const int base = blockIdx.y * HCH;
    const int lim = min(HCH, n - base);
    for (int i = threadIdx.x; i < HCH; i += blockDim.x) lh[i] = 0;
    __syncthreads();
    int stride = gridDim.x * blockDim.x;
    for (int e = blockIdx.x * blockDim.x + threadIdx.x; e < E; e += stride) {
        int d = dst[e] - base;
        if ((unsigned)d < (unsigned)lim) atomicAdd(&lh[d], 1);
    }
    __syncthreads();
    for (int i = threadIdx.x; i < lim; i += blockDim.x) {
        int v = lh[i];
        if (v) atomicAdd(&cnt[base + i], v);
    }
}

__global__ void hist_deg_kernel(const int* __restrict__ src, const float* __restrict__ w,
                                float* __restrict__ deg, int n, int E) {
    __shared__ float lhf[HCH];
    const int base = blockIdx.y * HCH;
    const int lim = min(HCH, n - base);
    for (int i = threadIdx.x; i < HCH; i += blockDim.x) lhf[i] = 0.f;
    __syncthreads();
    int stride = gridDim.x * blockDim.x;
    for (int e = blockIdx.x * blockDim.x + threadIdx.x; e < E; e += stride) {
        int s = src[e] - base;
        if ((unsigned)s < (unsigned)lim) atomicAdd(&lhf[s], w[e]);
    }
    __syncthreads();
    for (int i = threadIdx.x; i < lim; i += blockDim.x) {
        float v = lhf[i];
        if (v != 0.f) atomicAdd(&deg[base + i], v);
    }
}

__global__ void dinv_kernel(float* __restrict__ deg, int n) {
    int i = blockIdx.x * blockDim.x + threadIdx.x;
    if (i >= n) return;
    float d = deg[i];
    deg[i] = (d > 0.f) ? rsqrtf(d) : 0.f;
}

// ---------------- scan (row_ptr build) ----------------
__global__ void scan1_kernel(const int* __restrict__ cnt, int* __restrict__ incl,
                             int* __restrict__ bsum, int n) {
    __shared__ int sdata[256];
    int b = blockIdx.x, t = threadIdx.x;
    int base = b * 1024 + t * 4;
    int v[4];
    int s = 0;
#pragma unroll
    for (int k = 0; k < 4; ++k) {
        int idx = base + k;
        v[k] = (idx < n) ? cnt[idx] : 0;
        s += v[k];
    }
    sdata[t] = s;
    __syncthreads();
    for (int off = 1; off < 256; off <<= 1) {
        int y = (t >= off) ? sdata[t - off] : 0;
        __syncthreads();
        sdata[t] += y;
        __syncthreads();
    }
    int run = (t > 0) ? sdata[t - 1] : 0;
#pragma unroll
    for (int k = 0; k < 4; ++k) {
        int idx = base + k;
        run += v[k];
        if (idx < n) incl[idx] = run;
    }
    if (t == 255) bsum[b] = sdata[255];
}

__global__ void scan2_kernel(int* __restrict__ bsum, int nb) {
    __shared__ int sd[128];
    int t = threadIdx.x;
    sd[t] = (t < nb) ? bsum[t] : 0;
    __syncthreads();
    for (int off = 1; off < 128; off <<= 1) {
        int y = (t >= off) ? sd[t - off] : 0;
        __syncthreads();
        sd[t] += y;
        __syncthreads();
    }
    if (t < nb) bsum[t] = sd[t];
}

__global__ void scan3_kernel(int* __restrict__ incl, const int* __restrict__ bsum,
                             int n, int* __restrict__ rp) {
    int b = blockIdx.x, t = threadIdx.x;
    int add = (b > 0) ? bsum[b - 1] : 0;
    int base = b * 1024 + t * 4;
#pragma unroll
    for (int k = 0; k < 4; ++k) {
        int idx = base + k;
        if (idx < n) incl[idx] += add;
    }
    if (b == 0 && t == 0) rp[0] = 0;
}

__global__ void fill_copy_kernel(const int* __restrict__ rp, int* __restrict__ fill, int n) {
    int i = blockIdx.x * blockDim.x + threadIdx.x;
    if (i < n) fill[i] = rp[i];
}

__global__ void scatter_kernel(const int* __restrict__ src, const int* __restrict__ dst,
                               const float* __restrict__ w, const float* __restrict__ dinv,
                               int* __restrict__ fill, int2* __restrict__ cv, int E) {
    int e = blockIdx.x * blockDim.x + threadIdx.x;
    if (e >= E) return;
    int s = src[e], d = dst[e];
    float v = dinv[s] * w[e] * dinv[d];
    int o = atomicAdd(&fill[d], 1);
    int2 c;
    c.x = s;
    c.y = __float_as_int(v);
    cv[o] = c;
}

// ---------------- W transpose + bf16: Wt[m*G+g][f] = bf16(W[m][f][g]) ----------------
__global__ void wt_kernel(const float* __restrict__ W, ushort_t* __restrict__ Wt,
                          int F, int G) {
    int i = blockIdx.x * blockDim.x + threadIdx.x;
    int tot = 3 * F * G;
    if (i >= tot) return;
    int m = i / (F * G);
    int rem = i % (F * G);
    int f = rem / G, g = rem % G;
    Wt[((size_t)(m * G + g)) * F + f] = f2bf(W[i]);
}

// ---------------- MFMA GEMM: YA=H@(W0-W2), YB=H@W1, C16=bf16(H@W2) ----------------
// 256 threads = 4 waves; wave handles 16 rows; all 3*(G/16) col-tiles per wave.
// A-frag: lane holds 8 consecutive k of row (lane&15) at k0 = ks*32 + (lane>>4)*8.
// B-frag: lane holds 8 consecutive k of Wt row (= output col) (lane&15).
// C/D: col = lane&15, row = (lane>>4)*4 + reg   [verified layout, learn_hip m89/m91]
template <int F, int G, bool A_BF16>
__global__ __launch_bounds__(256) void gemm_mfma(const void* __restrict__ Hv,
                                                 const ushort_t* __restrict__ Wt,
                                                 float* __restrict__ YA,
                                                 float* __restrict__ YB,
                                                 ushort_t* __restrict__ C16, int n) {
    constexpr int CT = G / 16;
    const int tid = threadIdx.x;
    const int wave = tid >> 6;
    const int lane = tid & 63;
    const int l16 = lane & 15;
    const int lk8 = (lane >> 4) * 8;

    const int rowBase = blockIdx.x * 64 + wave * 16;
    int rA = rowBase + l16;
    if (rA >= n) rA = n - 1;

    f32x4 acc[3][CT];
#pragma unroll
    for (int m = 0; m < 3; ++m)
#pragma unroll
        for (int ct = 0; ct < CT; ++ct)
#pragma unroll
            for (int j = 0; j < 4; ++j) acc[m][ct][j] = 0.f;

#pragma unroll
    for (int ks = 0; ks < F; ks += 32) {
        short8 a;
        if constexpr (A_BF16) {
            a = *(const short8*)((const ushort_t*)Hv + (size_t)rA * F + ks + lk8);
        } else {
            const float* ap = (const float*)Hv + (size_t)rA * F + ks + lk8;
            float4 f0 = *(const float4*)ap;
            float4 f1 = *(const float4*)(ap + 4);
            a[0] = (short)f2bf(f0.x);
            a[1] = (short)f2bf(f0.y);
            a[2] = (short)f2bf(f0.z);
            a[3] = (short)f2bf(f0.w);
            a[4] = (short)f2bf(f1.x);
            a[5] = (short)f2bf(f1.y);
            a[6] = (short)f2bf(f1.z);
            a[7] = (short)f2bf(f1.w);
        }
#pragma unroll
        for (int m = 0; m < 3; ++m) {
#pragma unroll
            for (int ct = 0; ct < CT; ++ct) {
                short8 b = *(const short8*)(Wt + ((size_t)(m * G + ct * 16 + l16)) * F +
                                            ks + lk8);
                acc[m][ct] = __builtin_amdgcn_mfma_f32_16x16x32_bf16(a, b, acc[m][ct], 0, 0, 0);
            }
        }
    }

    const int r0 = rowBase + (lane >> 4) * 4;
#pragma unroll
    for (int ct = 0; ct < CT; ++ct) {
        const int col = ct * 16 + l16;
#pragma unroll
        for (int j = 0; j < 4; ++j) {
            int r = r0 + j;
            if (r < n) {
                float va = acc[0][ct][j] - acc[2][ct][j];
                float vb = acc[1][ct][j];
                float vc = acc[2][ct][j];
                YA[(size_t)r * G + col] = va;
                YB[(size_t)r * G + col] = vb;
                C16[(size_t)r * G + col] = f2bf(vc);
            }
        }
    }
}

// ---------------- spmm with bf16 gather ----------------
// MODE 1: S16 = bf16(Y - 2*A@Hg); MODE 2: H16 = bf16(relu(Y - A@Hg + b))
template <int G, int MODE>
__global__ __launch_bounds__(256) void spmm_bf16(const ushort_t* __restrict__ Hg,
                                                 const float* __restrict__ Yres,
                                                 const float* __restrict__ bias,
                                                 ushort_t* __restrict__ outS,
                                                 const int2* __restrict__ cv,
                                                 const int* __restrict__ rp, int n) {
    constexpr int TPR = G / 4;
    constexpr int RPB = 256 / TPR;
    int row = blockIdx.x * RPB + threadIdx.x / TPR;
    if (row >= n) return;
    int g = (threadIdx.x % TPR) * 4;
    float a0 = 0.f, a1 = 0.f, a2 = 0.f, a3 = 0.f;
    int e1 = rp[row + 1];
    for (int e = rp[row]; e < e1; ++e) {
        int2 c = cv[e];
        float v = __int_as_float(c.y);
        ushort4 hv = *(const ushort4*)(Hg + (size_t)c.x * G + g);
        a0 = fmaf(v, bf2f(hv.x), a0);
        a1 = fmaf(v, bf2f(hv.y), a1);
        a2 = fmaf(v, bf2f(hv.z), a2);
        a3 = fmaf(v, bf2f(hv.w), a3);
    }
    float4 yv = *(const float4*)(Yres + (size_t)row * G + g);
    ushort4 o;
    if (MODE == 1) {
        o.x = f2bf(yv.x - 2.f * a0);
        o.y = f2bf(yv.y - 2.f * a1);
        o.z = f2bf(yv.z - 2.f * a2);
        o.w = f2bf(yv.w - 2.f * a3);
    } else {
        o.x = f2bf(fmaxf(yv.x - a0 + bias[g + 0], 0.f));
        o.y = f2bf(fmaxf(yv.y - a1 + bias[g + 1], 0.f));
        o.z = f2bf(fmaxf(yv.z - a2 + bias[g + 2], 0.f));
        o.w = f2bf(fmaxf(yv.w - a3 + bias[g + 3], 0.f));
    }
    *(ushort4*)(outS + (size_t)row * G + g) = o;
}

// ---------------- layer 4 (fp32 tables; bf16 H3 input) ----------------

__global__ void gemm4(const ushort_t* __restrict__ H, const float* __restrict__ W,
                      float* __restrict__ YA, float* __restrict__ YB, float* __restrict__ C,
                      int n) {
    __shared__ float Ws[3 * 16 * 4];
    if (threadIdx.x < 192) Ws[threadIdx.x] = W[threadIdx.x];
    __syncthreads();
    int i = blockIdx.x * blockDim.x + threadIdx.x;
    if (i >= n) return;
    const ushort_t* h = H + (size_t)i * 16;
    float a[4], b[4], c[4];
#pragma unroll
    for (int g = 0; g < 4; ++g) a[g] = b[g] = c[g] = 0.f;
#pragma unroll
    for (int j = 0; j < 2; ++j) {
        short8 hv = *(const short8*)(h + j * 8);
#pragma unroll
        for (int k = 0; k < 8; ++k) {
            int f = j * 8 + k;
            float hf = bf2f((ushort_t)hv[k]);
#pragma unroll
            for (int g = 0; g < 4; ++g) {
                a[g] = fmaf(hf, Ws[f * 4 + g], a[g]);
                b[g] = fmaf(hf, Ws[64 + f * 4 + g], b[g]);
                c[g] = fmaf(hf, Ws[128 + f * 4 + g], c[g]);
            }
        }
    }
    float4 oa, ob, oc;
    oa.x = a[0] - c[0]; oa.y = a[1] - c[1]; oa.z = a[2] - c[2]; oa.w = a[3] - c[3];
    ob.x = b[0]; ob.y = b[1]; ob.z = b[2]; ob.w = b[3];
    oc.x = c[0]; oc.y = c[1]; oc.z = c[2]; oc.w = c[3];
    *(float4*)(YA + (size_t)i * 4) = oa;
    *(float4*)(YB + (size_t)i * 4) = ob;
    *(float4*)(C + (size_t)i * 4) = oc;
}

__global__ void spmm4(const float* __restrict__ C, const float* __restrict__ YB,
                      float* __restrict__ S, const int2* __restrict__ cv,
                      const int* __restrict__ rp, int n) {
    int row = blockIdx.x * blockDim.x + threadIdx.x;
    if (row >= n) return;
    float a0 = 0.f, a1 = 0.f, a2 = 0.f, a3 = 0.f;
    int e1 = rp[row + 1];
    for (int e = rp[row]; e < e1; ++e) {
        int2 c = cv[e];
        float v = __int_as_float(c.y);
        float4 cvv = *(const float4*)(C + (size_t)c.x * 4);
        a0 = fmaf(v, cvv.x, a0);
        a1 = fmaf(v, cvv.y, a1);
        a2 = fmaf(v, cvv.z, a2);
        a3 = fmaf(v, cvv.w, a3);
    }
    float4 yb = *(const float4*)(YB + (size_t)row * 4);
    float4 o;
    o.x = yb.x - 2.f * a0;
    o.y = yb.y - 2.f * a1;
    o.z = yb.z - 2.f * a2;
    o.w = yb.w - 2.f * a3;
    *(float4*)(S + (size_t)row * 4) = o;
}

__global__ void layer4_final(const float* __restrict__ S, const float* __restrict__ YA,
                             const float* __restrict__ b, float* __restrict__ out,
                             const int2* __restrict__ cv, const int* __restrict__ rp, int n) {
    int row = blockIdx.x * blockDim.x + threadIdx.x;
    if (row >= n) return;
    float a0 = 0.f, a1 = 0.f, a2 = 0.f, a3 = 0.f;
    int e1 = rp[row + 1];
    for (int e = rp[row]; e < e1; ++e) {
        int2 c = cv[e];
        float v = __int_as_float(c.y);
        float4 sv = *(const float4*)(S + (size_t)c.x * 4);
        a0 = fmaf(v, sv.x, a0);
        a1 = fmaf(v, sv.y, a1);
        a2 = fmaf(v, sv.z, a2);
        a3 = fmaf(v, sv.w, a3);
    }
    float4 ya = *(const float4*)(YA + (size_t)row * 4);
    float o0 = ya.x - a0 + b[0];
    float o1 = ya.y - a1 + b[1];
    float o2 = ya.z - a2 + b[2];
    float o3 = ya.w - a3 + b[3];
    float m = fmaxf(fmaxf(o0, o1), fmaxf(o2, o3));
    float s = expf(o0 - m) + expf(o1 - m) + expf(o2 - m) + expf(o3 - m);
    float ls = m + logf(s);
    float4 r;
    r.x = o0 - ls;
    r.y = o1 - ls;
    r.z = o2 - ls;
    r.w = o3 - ls;
    *(float4*)(out + (size_t)row * 4) = r;
}

// ---------------- launch ----------------

static inline char* align_up(char* p, size_t a) {
    return (char*)(((uintptr_t)p + a - 1) & ~(uintptr_t)(a - 1));
}

extern "C" void kernel_launch(void* const* d_in, const int* in_sizes, int n_in,
                              void* d_out, int out_size, void* d_ws, size_t ws_size,
                              hipStream_t stream) {
    const float* x = (const float*)d_in[0];
    const int* ei = (const int*)d_in[1];
    const float* ew = (const float*)d_in[2];
    const float* W1 = (const float*)d_in[3];
    const float* b1 = (const float*)d_in[4];
    const float* W2 = (const float*)d_in[5];
    const float* b2 = (const float*)d_in[6];
    const float* W3 = (const float*)d_in[7];
    const float* b3 = (const float*)d_in[8];
    const float* W4 = (const float*)d_in[9];
    const float* b4 = (const float*)d_in[10];
    float* out = (float*)d_out;

    const int n = in_sizes[0] / D_IN;  // 100000
    const int E = in_sizes[2];         // 1600000
    const int* src = ei;
    const int* dst = ei + E;

    char* p = (char*)d_ws;
    int2* cv = (int2*)p;          p += (size_t)E * 8;
    float* deg = (float*)p;       p += (size_t)n * 4;
    int* cnt = (int*)p;           p += (size_t)n * 4;
    int* fill = (int*)p;          p += (size_t)n * 4;
    int* rp = (int*)p;            p = align_up(p + (size_t)(n + 1) * 4, 64);
    int* bsum = (int*)p;          p = align_up(p + 512, 64);
    ushort_t* Wt1 = (ushort_t*)p; p = align_up(p + (size_t)192 * 128 * 2, 64);
    ushort_t* Wt2 = (ushort_t*)p; p = align_up(p + (size_t)96 * 64 * 2, 64);
    ushort_t* Wt3 = (ushort_t*)p; p = align_up(p + (size_t)48 * 32 * 2, 64);
    float* YA = (float*)p;        p = align_up(p + (size_t)n * 64 * 4, 64);
    float* YB = (float*)p;        p = align_up(p + (size_t)n * 64 * 4, 64);
    ushort_t* C16 = (ushort_t*)p; p = align_up(p + (size_t)n * 64 * 2, 64);
    ushort_t* S16 = (ushort_t*)p; p = align_up(p + (size_t)n * 64 * 2, 64);
    ushort_t* H1 = (ushort_t*)p;  p = align_up(p + (size_t)n * 64 * 2, 64);
    ushort_t* H2 = (ushort_t*)p;  p = align_up(p + (size_t)n * 32 * 2, 64);
    ushort_t* H3 = (ushort_t*)p;  p = align_up(p + (size_t)n * 16 * 2, 64);
    float* YA4 = (float*)p;       p = align_up(p + (size_t)n * 4 * 4, 64);
    float* YB4 = (float*)p;       p = align_up(p + (size_t)n * 4 * 4, 64);
    float* C4 = (float*)p;        p = align_up(p + (size_t)n * 4 * 4, 64);
    float* S4 = (float*)p;        p = align_up(p + (size_t)n * 4 * 4, 64);

    const int TB = 256;
    int eb = (E + TB - 1) / TB;
    int nb256 = (n + TB - 1) / TB;
    int nscan = (n + 1023) / 1024;
    int nch = (n + HCH - 1) / HCH;
    int gm = (n + 63) / 64;

    hipMemsetAsync(deg, 0, (size_t)n * 4, stream);
    hipMemsetAsync(cnt, 0, (size_t)n * 4, stream);
    {
        dim3 hg(128, nch);
        hist_cnt_kernel<<<hg, 256, 0, stream>>>(dst, cnt, n, E);
        hist_deg_kernel<<<hg, 256, 0, stream>>>(src, ew, deg, n, E);
    }
    dinv_kernel<<<nb256, TB, 0, stream>>>(deg, n);
    scan1_kernel<<<nscan, 256, 0, stream>>>(cnt, rp + 1, bsum, n);
    scan2_kernel<<<1, 128, 0, stream>>>(bsum, nscan);
    scan3_kernel<<<nscan, 256, 0, stream>>>(rp + 1, bsum, n, rp);
    fill_copy_kernel<<<nb256, TB, 0, stream>>>(rp, fill, n);
    scatter_kernel<<<eb, TB, 0, stream>>>(src, dst, ew, deg, fill, cv, E);

    // W transposes (tiny)
    wt_kernel<<<(3 * 128 * 64 + 255) / 256, 256, 0, stream>>>(W1, Wt1, 128, 64);
    wt_kernel<<<(3 * 64 * 32 + 255) / 256, 256, 0, stream>>>(W2, Wt2, 64, 32);
    wt_kernel<<<(3 * 32 * 16 + 255) / 256, 256, 0, stream>>>(W3, Wt3, 32, 16);

    // ---- layer 1: F=128, G=64 ----
    {
        constexpr int G = 64;
        gemm_mfma<128, G, false><<<gm, 256, 0, stream>>>(x, Wt1, YA, YB, C16, n);
        int sb = (n + (1024 / G) - 1) / (1024 / G);
        spmm_bf16<G, 1><<<sb, 256, 0, stream>>>(C16, YB, nullptr, S16, cv, rp, n);
        spmm_bf16<G, 2><<<sb, 256, 0, stream>>>(S16, YA, b1, H1, cv, rp, n);
    }
    // ---- layer 2: F=64, G=32 ----
    {
        constexpr int G = 32;
        gemm_mfma<64, G, true><<<gm, 256, 0, stream>>>(H1, Wt2, YA, YB, C16, n);
        int sb = (n + (1024 / G) - 1) / (1024 / G);
        spmm_bf16<G, 1><<<sb, 256, 0, stream>>>(C16, YB, nullptr, S16, cv, rp, n);
        spmm_bf16<G, 2><<<sb, 256, 0, stream>>>(S16, YA, b2, H2, cv, rp, n);
    }
    // ---- layer 3: F=32, G=16 ----
    {
        constexpr int G = 16;
        gemm_mfma<32, G, true><<<gm, 256, 0, stream>>>(H2, Wt3, YA, YB, C16, n);
        int sb = (n + (1024 / G) - 1) / (1024 / G);
        spmm_bf16<G, 1><<<sb, 256, 0, stream>>>(C16, YB, nullptr, S16, cv, rp, n);
        spmm_bf16<G, 2><<<sb, 256, 0, stream>>>(S16, YA, b3, H3, cv, rp, n);
    }
    // ---- layer 4: F=16, G=4 (fp32 tables) ----
    {
        gemm4<<<nb256, 256, 0, stream>>>(H3, W4, YA4, YB4, C4, n);
        spmm4<<<nb256, 256, 0, stream>>>(C4, YB4, S4, cv, rp, n);
        layer4_final<<<nb256, 256, 0, stream>>>(S4, YA4, b4, out, cv, rp, n);
    }
}